// Round 3
// baseline (142.439 us; speedup 1.0000x reference)
//
#include <hip/hip_runtime.h>
#include <math.h>

#define VOCAB 50257
#define BSZ   64
#define BEAM  8
#define NG    4     // NUM_GROUPS
#define MB    2     // beams per group
#define KC    2     // candidates per group
#define TLEN  128
#define NGRAM 2
#define SEG   16
#define SEGLEN 3142              // ceil(VOCAB/SEG); 16*3142 = 50272 >= 50257
#define ROWS  (BSZ * BEAM)       // 512
#define EPR   (SEG * 8)          // ws entries per row = 128

__device__ __forceinline__ bool better(float v1, int i1, float v2, int i2) {
    return (v1 > v2) || (v1 == v2 && i1 < i2);
}

struct Top2 { float v1, v2; int i1, i2; };

__device__ __forceinline__ void t2_init(Top2& t) {
    t.v1 = -INFINITY; t.v2 = -INFINITY; t.i1 = 0x7FFFFFFF; t.i2 = 0x7FFFFFFF;
}

__device__ __forceinline__ void t2_push(Top2& t, float v, int i) {
    if (better(v, i, t.v2, t.i2)) {
        if (better(v, i, t.v1, t.i1)) { t.v2 = t.v1; t.i2 = t.i1; t.v1 = v; t.i1 = i; }
        else                          { t.v2 = v;    t.i2 = i; }
    }
}

__device__ __forceinline__ void t2_merge(Top2& a, const Top2& b) {
    if (better(b.v1, b.i1, a.v1, a.i1)) {
        float nv2; int ni2;
        if (better(a.v1, a.i1, b.v2, b.i2)) { nv2 = a.v1; ni2 = a.i1; }
        else                                { nv2 = b.v2; ni2 = b.i2; }
        a.v1 = b.v1; a.i1 = b.i1; a.v2 = nv2; a.i2 = ni2;
    } else {
        if (better(b.v1, b.i1, a.v2, a.i2)) { a.v2 = b.v1; a.i2 = b.i1; }
    }
}

__device__ __forceinline__ void t8_push(float* tv, int* ti, float v, int i) {
    if (better(v, i, tv[7], ti[7])) {
        tv[7] = v; ti[7] = i;
        #pragma unroll
        for (int j = 7; j >= 1; --j) {
            if (better(tv[j], ti[j], tv[j-1], ti[j-1])) {
                float fv = tv[j]; tv[j] = tv[j-1]; tv[j-1] = fv;
                int   fi = ti[j]; ti[j] = ti[j-1]; ti[j-1] = fi;
            }
        }
    }
}

__device__ __forceinline__ float max4(float4 v) {
    return fmaxf(fmaxf(v.x, v.y), fmaxf(v.z, v.w));
}

__device__ __forceinline__ void push4(float* tv, int* ti, float4 v, int base) {
    t8_push(tv, ti, v.x, base);
    t8_push(tv, ti, v.y, base + 1);
    t8_push(tv, ti, v.z, base + 2);
    t8_push(tv, ti, v.w, base + 3);
}

// ---------------- Phase 1: per (row, segment) lex top-8 -> ws ----------------
__global__ __launch_bounds__(64) void dbs_phase1(
    const float* __restrict__ lprobs,   // (512, 50257)
    const int*   __restrict__ mask,     // (512, 2)
    float* __restrict__ wsv,            // (512*128)
    int*   __restrict__ wsi)            // (512*128)
{
    const int bid  = blockIdx.x;
    const int r    = bid >> 4;
    const int seg  = bid & 15;
    const int lane = threadIdx.x;

    if (mask[r * NGRAM] + mask[r * NGRAM + 1] != NGRAM) return;  // analytic in phase 2

    const size_t rowoff = (size_t)r * VOCAB;
    const float* row = lprobs + rowoff;
    const int start = seg * SEGLEN;
    const int end   = min(start + SEGLEN, VOCAB);

    float tv[8]; int ti[8];
    #pragma unroll
    for (int j = 0; j < 8; ++j) { tv[j] = -INFINITY; ti[j] = 0x7FFFFFFF; }

    // ---- alignment peel (row base is only 4B-aligned) ----
    const int mis  = (int)((rowoff + start) & 3);
    const int pre  = (4 - mis) & 3;
    if (lane < pre && start + lane < end) {
        t8_push(tv, ti, row[start + lane], start + lane);
    }
    const int vstart = start + pre;                  // (rowoff+vstart) % 4 == 0
    const int n4     = (end > vstart) ? ((end - vstart) >> 2) : 0;
    const float4* vrow = (const float4*)(row + vstart);

    // ---- vector body: 4x unrolled, max-filtered (strict '>' is lex-correct:
    //      within a thread indices strictly increase, so a tie with tv[7]
    //      always has a larger index and can be skipped) ----
    int j = lane;
    for (; j + 192 < n4; j += 256) {
        const float4 v0 = vrow[j];
        const float4 v1 = vrow[j + 64];
        const float4 v2 = vrow[j + 128];
        const float4 v3 = vrow[j + 192];
        const float m0 = max4(v0), m1 = max4(v1), m2 = max4(v2), m3 = max4(v3);
        const float m  = fmaxf(fmaxf(m0, m1), fmaxf(m2, m3));
        if (m > tv[7]) {
            if (m0 > tv[7]) push4(tv, ti, v0, vstart + 4*j);
            if (m1 > tv[7]) push4(tv, ti, v1, vstart + 4*(j + 64));
            if (m2 > tv[7]) push4(tv, ti, v2, vstart + 4*(j + 128));
            if (m3 > tv[7]) push4(tv, ti, v3, vstart + 4*(j + 192));
        }
    }
    for (; j < n4; j += 64) {
        const float4 v = vrow[j];
        if (max4(v) > tv[7]) push4(tv, ti, v, vstart + 4*j);
    }
    // ---- scalar tail (<=3 elements) ----
    const int tstart = vstart + 4*n4;
    if (tstart + lane < end) {
        t8_push(tv, ti, row[tstart + lane], tstart + lane);
    }

    // ---- wave pop-merge: 8 rounds of butterfly argmax over sorted heads ----
    const int base = r * EPR + seg * 8;
    #pragma unroll
    for (int round = 0; round < 8; ++round) {
        float mv = tv[0]; int mi = ti[0];
        #pragma unroll
        for (int off = 32; off > 0; off >>= 1) {
            const float ov = __shfl_xor(mv, off);
            const int   oi = __shfl_xor(mi, off);
            if (better(ov, oi, mv, mi)) { mv = ov; mi = oi; }
        }
        if (lane == 0) { wsv[base + round] = mv; wsi[base + round] = mi; }
        if (tv[0] == mv && ti[0] == mi) {        // unique owner (indices distinct)
            #pragma unroll
            for (int jj = 0; jj < 7; ++jj) { tv[jj] = tv[jj+1]; ti[jj] = ti[jj+1]; }
            tv[7] = -INFINITY; ti[7] = 0x7FFFFFFF;
        }
    }
}

// ---------------- Phase 2: per-batch sequential group chain on candidates ----
__global__ __launch_bounds__(64) void dbs_phase2(
    const float* __restrict__ scores,   // (64,8,128)
    const float* __restrict__ overlap,  // (64,4,4)
    const int*   __restrict__ obi,      // (64,)
    const int*   __restrict__ lastn,    // (64,8,1)
    const int*   __restrict__ mask,     // (64,8,2)
    const int*   __restrict__ stepp,    // (1,)
    const float* __restrict__ wsv,
    const int*   __restrict__ wsi,
    float*       __restrict__ out)      // 2560 floats
{
    const int b   = blockIdx.x;
    const int tid = threadIdx.x;
    const int step = stepp[0];
    const int ob   = obi[b];

    __shared__ float s_sc[BEAM];
    __shared__ int   s_valid[BEAM];
    __shared__ float s_pen[(NG-1)*KC];
    __shared__ int   s_penidx[(NG-1)*KC];
    __shared__ float s_selv[NG][KC];
    __shared__ int   s_seli[NG][KC];
    __shared__ int   s_selm[NG][KC];

    if (tid < BEAM) {
        const int* mk = mask + ((size_t)b * BEAM + tid) * NGRAM;
        s_valid[tid] = (mk[0] + mk[1]) == NGRAM;
        s_sc[tid]    = scores[((size_t)b * BEAM + tid) * TLEN + (step - 1)];
    }
    __syncthreads();

    for (int g = 0; g < NG; ++g) {
        if (tid == 0) {
            for (int j = 0; j < g; ++j) {
                const float pen = 1.0f + overlap[((size_t)ob * NG + g) * NG + j];
                s_penidx[j*KC + 0] = s_seli[j][0]; s_pen[j*KC + 0] = pen;
                s_penidx[j*KC + 1] = s_seli[j][1]; s_pen[j*KC + 1] = pen;
            }
        }
        __syncthreads();

        const int np = KC * g;            // block-uniform
        Top2 t; t2_init(t);
        for (int m = 0; m < MB; ++m) {
            const int beam = m * NG + g;
            if (s_valid[beam]) {          // block-uniform branch
                const int r = b * BEAM + beam;
                #pragma unroll
                for (int cc = 0; cc < EPR / 64; ++cc) {
                    const int c = tid + cc * 64;
                    const float v   = wsv[r * EPR + c];
                    const int   idx = wsi[r * EPR + c];
                    float dv = 0.0f;
                    #pragma unroll
                    for (int p = 0; p < (NG-1)*KC; ++p)
                        if (p < np && s_penidx[p] == idx) dv += s_pen[p];
                    t2_push(t, v - 0.5f * dv + s_sc[beam], m * VOCAB + idx);
                }
            } else if (tid < KC) {
                // invalid row: constant sc -> best two flat idx m*V, m*V+1
                t2_push(t, s_sc[beam], m * VOCAB + tid);
            }
        }

        for (int off = 32; off > 0; off >>= 1) {
            Top2 o;
            o.v1 = __shfl_down(t.v1, off); o.i1 = __shfl_down(t.i1, off);
            o.v2 = __shfl_down(t.v2, off); o.i2 = __shfl_down(t.i2, off);
            t2_merge(t, o);
        }
        if (tid == 0) {
            s_selv[g][0] = t.v1; s_seli[g][0] = t.i1 % VOCAB; s_selm[g][0] = t.i1 / VOCAB;
            s_selv[g][1] = t.v2; s_seli[g][1] = t.i2 % VOCAB; s_selm[g][1] = t.i2 / VOCAB;
        }
        __syncthreads();
    }

    // ---- outputs: scores[0,512) indices[512,1024) beams[1024,1536) overlap[1536,2560)
    if (tid < KC * NG) {                  // i = m*NG + g
        const int i = tid;
        const int m = i / NG, g = i % NG;
        out[(size_t)b * BEAM + i]        = s_selv[g][m];
        out[512 + (size_t)b * BEAM + i]  = (float)s_seli[g][m];
        out[1024 + (size_t)b * BEAM + i] = (float)(s_selm[g][m] * NG + g);
    }
    if (tid >= 16 && tid < 16 + NG * NG) {
        const int q  = tid - 16;
        const int g1 = q / NG, g2 = q % NG;
        int ov = 0;
        for (int m = 0; m < MB; ++m) {
            const int i1 = m * NG + g1, i2 = m * NG + g2;
            const int p1a = lastn[(size_t)b * BEAM + i1];
            const int p2a = lastn[(size_t)b * BEAM + i2];
            const int p1b = s_seli[g1][m];
            const int p2b = s_seli[g2][m];
            const int* mk1 = mask + ((size_t)b * BEAM + i1) * NGRAM;
            const int* mk2 = mask + ((size_t)b * BEAM + i2) * NGRAM;
            const bool e0 = (p1a == p2a) && (mk1[0] != 0) && (mk2[0] != 0);
            const bool e1 = (p1b == p2b) && (mk1[1] != 0) && (mk2[1] != 0);
            ov += (e0 && e1) ? 1 : 0;
        }
        out[1536 + (size_t)ob * (NG * NG) + q] =
            (overlap[(size_t)ob * (NG * NG) + q] + (float)ov) * 0.5f;
    }
}

extern "C" void kernel_launch(void* const* d_in, const int* in_sizes, int n_in,
                              void* d_out, int out_size, void* d_ws, size_t ws_size,
                              hipStream_t stream) {
    const float* lprobs  = (const float*)d_in[0];
    const float* scores  = (const float*)d_in[1];
    const float* overlap = (const float*)d_in[2];
    const int*   obi     = (const int*)d_in[3];
    const int*   lastn   = (const int*)d_in[4];
    const int*   mask    = (const int*)d_in[5];
    const int*   stepp   = (const int*)d_in[6];
    float*       out     = (float*)d_out;

    float* wsv = (float*)d_ws;
    int*   wsi = (int*)((char*)d_ws + (size_t)ROWS * EPR * sizeof(float));

    dbs_phase1<<<ROWS * SEG, 64, 0, stream>>>(lprobs, mask, wsv, wsi);
    dbs_phase2<<<BSZ, 64, 0, stream>>>(scores, overlap, obi, lastn, mask, stepp,
                                       wsv, wsi, out);
}

// Round 4
// 31.253 us; speedup vs baseline: 4.5576x; 4.5576x over previous
//
#include <hip/hip_runtime.h>
#include <math.h>

#define VOCAB 50257
#define BSZ   64
#define BEAM  8
#define NG    4     // NUM_GROUPS
#define MB    2     // beams per group
#define KC    2     // candidates per group
#define TLEN  128
#define NGRAM 2
#define SEG    64
#define SEGLEN 786               // 64*786 = 50304 >= 50257; n4 <= 196 < 256
#define ROWS  (BSZ * BEAM)       // 512

__device__ __forceinline__ bool better(float v1, int i1, float v2, int i2) {
    return (v1 > v2) || (v1 == v2 && i1 < i2);
}

struct Top2 { float v1, v2; int i1, i2; };

__device__ __forceinline__ void t2_init(Top2& t) {
    t.v1 = -INFINITY; t.v2 = -INFINITY; t.i1 = 0x7FFFFFFF; t.i2 = 0x7FFFFFFF;
}

__device__ __forceinline__ void t2_push(Top2& t, float v, int i) {
    if (better(v, i, t.v2, t.i2)) {
        if (better(v, i, t.v1, t.i1)) { t.v2 = t.v1; t.i2 = t.i1; t.v1 = v; t.i1 = i; }
        else                          { t.v2 = v;    t.i2 = i; }
    }
}

__device__ __forceinline__ void t2_merge(Top2& a, const Top2& b) {
    if (better(b.v1, b.i1, a.v1, a.i1)) {
        float nv2; int ni2;
        if (better(a.v1, a.i1, b.v2, b.i2)) { nv2 = a.v1; ni2 = a.i1; }
        else                                { nv2 = b.v2; ni2 = b.i2; }
        a.v1 = b.v1; a.i1 = b.i1; a.v2 = nv2; a.i2 = ni2;
    } else {
        if (better(b.v1, b.i1, a.v2, a.i2)) { a.v2 = b.v1; a.i2 = b.i1; }
    }
}

__device__ __forceinline__ float max4(float4 v) {
    return fmaxf(fmaxf(v.x, v.y), fmaxf(v.z, v.w));
}

// ---------- Phase A: per (row, segment) max -> wsmax; zero wscnt ------------
__global__ __launch_bounds__(256) void dbs_segmax(
    const float* __restrict__ lprobs,   // (512, 50257)
    const int*   __restrict__ mask,     // (512, 2)
    float* __restrict__ wsmax,          // (512, 64)
    int*   __restrict__ wscnt)          // (512,)
{
    const int blk  = blockIdx.x;        // 512 rows * 16
    const int r    = blk >> 4;
    const int oct  = blk & 15;
    const int tid  = threadIdx.x;
    const int w    = tid >> 6, lane = tid & 63;

    if (oct == 0 && tid == 0) wscnt[r] = 0;   // re-zero every call (graph replay)
    if (mask[r * NGRAM] + mask[r * NGRAM + 1] != NGRAM) return;  // invalid row

    const int seg = oct * 4 + w;
    const size_t rowoff = (size_t)r * VOCAB;
    const float* row = lprobs + rowoff;
    const int start = seg * SEGLEN;
    const int end   = min(start + SEGLEN, VOCAB);

    float m = -INFINITY;
    const int mis = (int)((rowoff + start) & 3);
    const int pre = (4 - mis) & 3;
    if (lane < pre && start + lane < end) m = row[start + lane];
    const int vstart = start + pre;
    const int n4 = (end > vstart) ? ((end - vstart) >> 2) : 0;   // <= 196
    const float4* vrow = (const float4*)(row + vstart);

    float a0 = -INFINITY, a1 = -INFINITY, a2 = -INFINITY, a3 = -INFINITY;
    if (lane        < n4) a0 = max4(vrow[lane]);
    if (lane +  64  < n4) a1 = max4(vrow[lane + 64]);
    if (lane + 128  < n4) a2 = max4(vrow[lane + 128]);
    if (lane + 192  < n4) a3 = max4(vrow[lane + 192]);
    m = fmaxf(m, fmaxf(fmaxf(a0, a1), fmaxf(a2, a3)));
    const int tstart = vstart + 4 * n4;
    if (tstart + lane < end) m = fmaxf(m, row[tstart + lane]);

    #pragma unroll
    for (int off = 32; off > 0; off >>= 1) m = fmaxf(m, __shfl_xor(m, off));
    if (lane == 0) wsmax[r * SEG + seg] = m;
}

// ---------- Phase B: tau = 8th largest segmax; compact v >= tau -------------
__device__ __forceinline__ void emit_cand(float v, int idx, int r, int cap,
                                          int* wscnt, float* wscv, int* wsci) {
    const int p = atomicAdd(&wscnt[r], 1);
    if (p < cap) {
        wscv[(size_t)r * cap + p] = v;
        wsci[(size_t)r * cap + p] = idx;
    }
}

__global__ __launch_bounds__(256) void dbs_compact(
    const float* __restrict__ lprobs,
    const int*   __restrict__ mask,
    const float* __restrict__ wsmax,
    int*   __restrict__ wscnt,
    float* __restrict__ wscv,
    int*   __restrict__ wsci,
    int cap)
{
    const int blk  = blockIdx.x;
    const int r    = blk >> 4;
    const int oct  = blk & 15;
    const int tid  = threadIdx.x;
    const int w    = tid >> 6, lane = tid & 63;

    if (mask[r * NGRAM] + mask[r * NGRAM + 1] != NGRAM) return;

    // tau: 8th largest (lex on (value, segidx)) of the row's 64 segment maxima
    const float mym = wsmax[r * SEG + lane];
    int rank = 0;
    for (int i = 0; i < SEG; ++i) {
        const float om = __shfl(mym, i);
        rank += better(om, i, mym, lane) ? 1 : 0;
    }
    const unsigned long long bm = __ballot(rank == 7);
    const int src = __ffsll(bm) - 1;
    const float tau = __shfl(mym, src);

    const int seg = oct * 4 + w;
    const size_t rowoff = (size_t)r * VOCAB;
    const float* row = lprobs + rowoff;
    const int start = seg * SEGLEN;
    const int end   = min(start + SEGLEN, VOCAB);

    const int mis = (int)((rowoff + start) & 3);
    const int pre = (4 - mis) & 3;
    if (lane < pre && start + lane < end) {
        const float v = row[start + lane];
        if (v >= tau) emit_cand(v, start + lane, r, cap, wscnt, wscv, wsci);
    }
    const int vstart = start + pre;
    const int n4 = (end > vstart) ? ((end - vstart) >> 2) : 0;
    const float4* vrow = (const float4*)(row + vstart);

    #pragma unroll
    for (int u = 0; u < 4; ++u) {
        const int jj = lane + u * 64;
        if (jj < n4) {
            const float4 v = vrow[jj];
            if (max4(v) >= tau) {
                const int base = vstart + 4 * jj;
                if (v.x >= tau) emit_cand(v.x, base,     r, cap, wscnt, wscv, wsci);
                if (v.y >= tau) emit_cand(v.y, base + 1, r, cap, wscnt, wscv, wsci);
                if (v.z >= tau) emit_cand(v.z, base + 2, r, cap, wscnt, wscv, wsci);
                if (v.w >= tau) emit_cand(v.w, base + 3, r, cap, wscnt, wscv, wsci);
            }
        }
    }
    const int tstart = vstart + 4 * n4;
    if (tstart + lane < end) {
        const float v = row[tstart + lane];
        if (v >= tau) emit_cand(v, tstart + lane, r, cap, wscnt, wscv, wsci);
    }
}

// ---------- Phase C: per-batch sequential group chain on candidates ---------
__global__ __launch_bounds__(64) void dbs_final(
    const float* __restrict__ scores,   // (64,8,128)
    const float* __restrict__ overlap,  // (64,4,4)
    const int*   __restrict__ obi,      // (64,)
    const int*   __restrict__ lastn,    // (64,8,1)
    const int*   __restrict__ mask,     // (64,8,2)
    const int*   __restrict__ stepp,    // (1,)
    const int*   __restrict__ wscnt,
    const float* __restrict__ wscv,
    const int*   __restrict__ wsci,
    int cap,
    float*       __restrict__ out)      // 2560 floats
{
    const int b   = blockIdx.x;
    const int tid = threadIdx.x;
    const int step = stepp[0];
    const int ob   = obi[b];

    __shared__ float s_sc[BEAM];
    __shared__ int   s_valid[BEAM];
    __shared__ float s_pen[(NG-1)*KC];
    __shared__ int   s_penidx[(NG-1)*KC];
    __shared__ float s_selv[NG][KC];
    __shared__ int   s_seli[NG][KC];
    __shared__ int   s_selm[NG][KC];

    if (tid < BEAM) {
        const int* mk = mask + ((size_t)b * BEAM + tid) * NGRAM;
        s_valid[tid] = (mk[0] + mk[1]) == NGRAM;
        s_sc[tid]    = scores[((size_t)b * BEAM + tid) * TLEN + (step - 1)];
    }
    __syncthreads();

    for (int g = 0; g < NG; ++g) {
        if (tid == 0) {
            for (int j = 0; j < g; ++j) {
                const float pen = 1.0f + overlap[((size_t)ob * NG + g) * NG + j];
                s_penidx[j*KC + 0] = s_seli[j][0]; s_pen[j*KC + 0] = pen;
                s_penidx[j*KC + 1] = s_seli[j][1]; s_pen[j*KC + 1] = pen;
            }
        }
        __syncthreads();

        const int np = KC * g;            // block-uniform
        Top2 t; t2_init(t);
        for (int m = 0; m < MB; ++m) {
            const int beam = m * NG + g;
            if (s_valid[beam]) {          // block-uniform branch
                const int r = b * BEAM + beam;
                const int n = min(wscnt[r], cap);
                for (int c = tid; c < n; c += 64) {
                    const float v   = wscv[(size_t)r * cap + c];
                    const int   idx = wsci[(size_t)r * cap + c];
                    float dv = 0.0f;
                    #pragma unroll
                    for (int p = 0; p < (NG-1)*KC; ++p)
                        if (p < np && s_penidx[p] == idx) dv += s_pen[p];
                    t2_push(t, v - 0.5f * dv + s_sc[beam], m * VOCAB + idx);
                }
            } else if (tid < KC) {
                // invalid row: constant sc -> best two flat idx m*V, m*V+1
                t2_push(t, s_sc[beam], m * VOCAB + tid);
            }
        }

        #pragma unroll
        for (int off = 32; off > 0; off >>= 1) {
            Top2 o;
            o.v1 = __shfl_down(t.v1, off); o.i1 = __shfl_down(t.i1, off);
            o.v2 = __shfl_down(t.v2, off); o.i2 = __shfl_down(t.i2, off);
            t2_merge(t, o);
        }
        if (tid == 0) {
            s_selv[g][0] = t.v1; s_seli[g][0] = t.i1 % VOCAB; s_selm[g][0] = t.i1 / VOCAB;
            s_selv[g][1] = t.v2; s_seli[g][1] = t.i2 % VOCAB; s_selm[g][1] = t.i2 / VOCAB;
        }
        __syncthreads();
    }

    // ---- outputs: scores[0,512) indices[512,1024) beams[1024,1536) overlap[1536,2560)
    if (tid < KC * NG) {                  // i = m*NG + g
        const int i = tid;
        const int m = i / NG, g = i % NG;
        out[(size_t)b * BEAM + i]        = s_selv[g][m];
        out[512 + (size_t)b * BEAM + i]  = (float)s_seli[g][m];
        out[1024 + (size_t)b * BEAM + i] = (float)(s_selm[g][m] * NG + g);
    }
    if (tid >= 16 && tid < 16 + NG * NG) {
        const int q  = tid - 16;
        const int g1 = q / NG, g2 = q % NG;
        int ov = 0;
        for (int m = 0; m < MB; ++m) {
            const int i1 = m * NG + g1, i2 = m * NG + g2;
            const int p1a = lastn[(size_t)b * BEAM + i1];
            const int p2a = lastn[(size_t)b * BEAM + i2];
            const int p1b = s_seli[g1][m];
            const int p2b = s_seli[g2][m];
            const int* mk1 = mask + ((size_t)b * BEAM + i1) * NGRAM;
            const int* mk2 = mask + ((size_t)b * BEAM + i2) * NGRAM;
            const bool e0 = (p1a == p2a) && (mk1[0] != 0) && (mk2[0] != 0);
            const bool e1 = (p1b == p2b) && (mk1[1] != 0) && (mk2[1] != 0);
            ov += (e0 && e1) ? 1 : 0;
        }
        out[1536 + (size_t)ob * (NG * NG) + q] =
            (overlap[(size_t)ob * (NG * NG) + q] + (float)ov) * 0.5f;
    }
}

extern "C" void kernel_launch(void* const* d_in, const int* in_sizes, int n_in,
                              void* d_out, int out_size, void* d_ws, size_t ws_size,
                              hipStream_t stream) {
    const float* lprobs  = (const float*)d_in[0];
    const float* scores  = (const float*)d_in[1];
    const float* overlap = (const float*)d_in[2];
    const int*   obi     = (const int*)d_in[3];
    const int*   lastn   = (const int*)d_in[4];
    const int*   mask    = (const int*)d_in[5];
    const int*   stepp   = (const int*)d_in[6];
    float*       out     = (float*)d_out;

    // ws layout: wsmax (512*64 f32 = 128KB) | wscnt (512 i32 = 2KB) | wscv | wsci
    float* wsmax = (float*)d_ws;
    int*   wscnt = (int*)((char*)d_ws + (size_t)ROWS * SEG * 4);
    const size_t fixed = (size_t)ROWS * SEG * 4 + ROWS * 4;
    size_t avail = (ws_size > fixed) ? (ws_size - fixed) : 0;
    int cap = (int)(avail / ((size_t)ROWS * 8));
    if (cap > 256) cap = 256;
    if (cap < 8)   cap = 8;      // should never happen (ws >= 512KB observed)
    float* wscv = (float*)((char*)d_ws + fixed);
    int*   wsci = (int*)((char*)d_ws + fixed + (size_t)ROWS * cap * 4);

    dbs_segmax <<<ROWS * 16, 256, 0, stream>>>(lprobs, mask, wsmax, wscnt);
    dbs_compact<<<ROWS * 16, 256, 0, stream>>>(lprobs, mask, wsmax, wscnt,
                                               wscv, wsci, cap);
    dbs_final  <<<BSZ, 64, 0, stream>>>(scores, overlap, obi, lastn, mask, stepp,
                                        wscnt, wscv, wsci, cap, out);
}

// Round 5
// 27.201 us; speedup vs baseline: 5.2366x; 1.1490x over previous
//
#include <hip/hip_runtime.h>
#include <math.h>

#define VOCAB 50257
#define BSZ   64
#define BEAM  8
#define NG    4     // NUM_GROUPS
#define MB    2     // beams per group
#define KC    2     // candidates per group
#define TLEN  128
#define NGRAM 2
#define SEG    64
#define SEGLEN 786               // 64*786 = 50304 >= 50257; n4 <= 196
#define ROWS  (BSZ * BEAM)       // 512
#define CAP   1024               // candidate capacity per row (E[cnt] ~ 34)

__device__ __forceinline__ bool better(float v1, int i1, float v2, int i2) {
    return (v1 > v2) || (v1 == v2 && i1 < i2);
}

struct Top2 { float v1, v2; int i1, i2; };

__device__ __forceinline__ void t2_init(Top2& t) {
    t.v1 = -INFINITY; t.v2 = -INFINITY; t.i1 = 0x7FFFFFFF; t.i2 = 0x7FFFFFFF;
}

__device__ __forceinline__ void t2_push(Top2& t, float v, int i) {
    if (better(v, i, t.v2, t.i2)) {
        if (better(v, i, t.v1, t.i1)) { t.v2 = t.v1; t.i2 = t.i1; t.v1 = v; t.i1 = i; }
        else                          { t.v2 = v;    t.i2 = i; }
    }
}

__device__ __forceinline__ void t2_merge(Top2& a, const Top2& b) {
    if (better(b.v1, b.i1, a.v1, a.i1)) {
        float nv2; int ni2;
        if (better(a.v1, a.i1, b.v2, b.i2)) { nv2 = a.v1; ni2 = a.i1; }
        else                                { nv2 = b.v2; ni2 = b.i2; }
        a.v1 = b.v1; a.i1 = b.i1; a.v2 = nv2; a.i2 = ni2;
    } else {
        if (better(b.v1, b.i1, a.v2, a.i2)) { a.v2 = b.v1; a.i2 = b.i1; }
    }
}

__device__ __forceinline__ float max4(float4 v) {
    return fmaxf(fmaxf(v.x, v.y), fmaxf(v.z, v.w));
}

// ------- Fused phase AB: block per row; segmax -> tau -> compact ------------
__global__ __launch_bounds__(1024) void dbs_candidates(
    const float* __restrict__ lprobs,   // (512, 50257)
    const int*   __restrict__ mask,     // (512, 2)
    int*   __restrict__ wscnt,          // (512,)
    float* __restrict__ wscv,           // (512, CAP)
    int*   __restrict__ wsci)           // (512, CAP)
{
    const int r    = blockIdx.x;
    const int tid  = threadIdx.x;
    const int w    = tid >> 6, lane = tid & 63;

    if (mask[r * NGRAM] + mask[r * NGRAM + 1] != NGRAM) return;  // invalid row

    __shared__ float s_max[SEG];
    __shared__ float s_tau;
    __shared__ int   s_cnt;
    __shared__ float s_cv[CAP];
    __shared__ int   s_ci[CAP];

    if (tid == 0) s_cnt = 0;

    const size_t rowoff = (size_t)r * VOCAB;
    const float* row = lprobs + rowoff;

    // ---- pass 1: per-segment max (wave w owns segments 4w..4w+3) ----
    #pragma unroll
    for (int s = 0; s < 4; ++s) {
        const int seg   = w * 4 + s;
        const int start = seg * SEGLEN;
        const int end   = min(start + SEGLEN, VOCAB);
        const int mis   = (int)((rowoff + start) & 3);
        const int pre   = (4 - mis) & 3;

        float m = -INFINITY;
        if (lane < pre && start + lane < end) m = row[start + lane];
        const int vstart = start + pre;
        const int n4 = (end > vstart) ? ((end - vstart) >> 2) : 0;   // <= 196
        const float4* vrow = (const float4*)(row + vstart);

        float a0 = -INFINITY, a1 = -INFINITY, a2 = -INFINITY, a3 = -INFINITY;
        if (lane       < n4) a0 = max4(vrow[lane]);
        if (lane +  64 < n4) a1 = max4(vrow[lane + 64]);
        if (lane + 128 < n4) a2 = max4(vrow[lane + 128]);
        if (lane + 192 < n4) a3 = max4(vrow[lane + 192]);
        m = fmaxf(m, fmaxf(fmaxf(a0, a1), fmaxf(a2, a3)));
        const int tstart = vstart + 4 * n4;
        if (tstart + lane < end) m = fmaxf(m, row[tstart + lane]);

        #pragma unroll
        for (int off = 32; off > 0; off >>= 1) m = fmaxf(m, __shfl_xor(m, off));
        if (lane == 0) s_max[seg] = m;
    }
    __syncthreads();

    // ---- tau = 8th largest (lex) of the 64 segment maxima (wave 0) ----
    if (w == 0) {
        const float mym = s_max[lane];
        int rank = 0;
        for (int i = 0; i < SEG; ++i) {
            const float om = __shfl(mym, i);
            rank += better(om, i, mym, lane) ? 1 : 0;
        }
        if (rank == 7) s_tau = mym;     // exactly one lane (ranks are a permutation)
    }
    __syncthreads();
    const float tau = s_tau;

    // ---- pass 2: rescan (L2-resident), compact v >= tau into LDS ----
    #pragma unroll
    for (int s = 0; s < 4; ++s) {
        const int seg   = w * 4 + s;
        const int start = seg * SEGLEN;
        const int end   = min(start + SEGLEN, VOCAB);
        const int mis   = (int)((rowoff + start) & 3);
        const int pre   = (4 - mis) & 3;

        if (lane < pre && start + lane < end) {
            const float v = row[start + lane];
            if (v >= tau) {
                const int p = atomicAdd(&s_cnt, 1);
                if (p < CAP) { s_cv[p] = v; s_ci[p] = start + lane; }
            }
        }
        const int vstart = start + pre;
        const int n4 = (end > vstart) ? ((end - vstart) >> 2) : 0;
        const float4* vrow = (const float4*)(row + vstart);

        #pragma unroll
        for (int u = 0; u < 4; ++u) {
            const int jj = lane + u * 64;
            if (jj < n4) {
                const float4 v = vrow[jj];
                if (max4(v) >= tau) {
                    const int base = vstart + 4 * jj;
                    #pragma unroll
                    for (int e = 0; e < 4; ++e) {
                        const float ve = (e == 0) ? v.x : (e == 1) ? v.y
                                       : (e == 2) ? v.z : v.w;
                        if (ve >= tau) {
                            const int p = atomicAdd(&s_cnt, 1);
                            if (p < CAP) { s_cv[p] = ve; s_ci[p] = base + e; }
                        }
                    }
                }
            }
        }
        const int tstart = vstart + 4 * n4;
        if (tstart + lane < end) {
            const float v = row[tstart + lane];
            if (v >= tau) {
                const int p = atomicAdd(&s_cnt, 1);
                if (p < CAP) { s_cv[p] = v; s_ci[p] = tstart + lane; }
            }
        }
    }
    __syncthreads();

    // ---- emit: count + coalesced candidate dump ----
    const int cnt = min(s_cnt, CAP);
    if (tid == 0) wscnt[r] = cnt;
    for (int c = tid; c < cnt; c += 1024) {
        wscv[(size_t)r * CAP + c] = s_cv[c];
        wsci[(size_t)r * CAP + c] = s_ci[c];
    }
}

// ---------- Final: per-batch sequential group chain on candidates -----------
__global__ __launch_bounds__(64) void dbs_final(
    const float* __restrict__ scores,   // (64,8,128)
    const float* __restrict__ overlap,  // (64,4,4)
    const int*   __restrict__ obi,      // (64,)
    const int*   __restrict__ lastn,    // (64,8,1)
    const int*   __restrict__ mask,     // (64,8,2)
    const int*   __restrict__ stepp,    // (1,)
    const int*   __restrict__ wscnt,
    const float* __restrict__ wscv,
    const int*   __restrict__ wsci,
    float*       __restrict__ out)      // 2560 floats
{
    const int b   = blockIdx.x;
    const int tid = threadIdx.x;
    const int step = stepp[0];
    const int ob   = obi[b];

    __shared__ float s_sc[BEAM];
    __shared__ int   s_valid[BEAM];
    __shared__ float s_pen[(NG-1)*KC];
    __shared__ int   s_penidx[(NG-1)*KC];
    __shared__ float s_selv[NG][KC];
    __shared__ int   s_seli[NG][KC];
    __shared__ int   s_selm[NG][KC];

    if (tid < BEAM) {
        const int* mk = mask + ((size_t)b * BEAM + tid) * NGRAM;
        s_valid[tid] = (mk[0] + mk[1]) == NGRAM;
        s_sc[tid]    = scores[((size_t)b * BEAM + tid) * TLEN + (step - 1)];
    }
    __syncthreads();

    for (int g = 0; g < NG; ++g) {
        if (tid == 0) {
            for (int j = 0; j < g; ++j) {
                const float pen = 1.0f + overlap[((size_t)ob * NG + g) * NG + j];
                s_penidx[j*KC + 0] = s_seli[j][0]; s_pen[j*KC + 0] = pen;
                s_penidx[j*KC + 1] = s_seli[j][1]; s_pen[j*KC + 1] = pen;
            }
        }
        __syncthreads();

        const int np = KC * g;            // block-uniform
        Top2 t; t2_init(t);
        for (int m = 0; m < MB; ++m) {
            const int beam = m * NG + g;
            if (s_valid[beam]) {          // block-uniform branch
                const int r = b * BEAM + beam;
                const int n = wscnt[r];
                for (int c = tid; c < n; c += 64) {
                    const float v   = wscv[(size_t)r * CAP + c];
                    const int   idx = wsci[(size_t)r * CAP + c];
                    float dv = 0.0f;
                    #pragma unroll
                    for (int p = 0; p < (NG-1)*KC; ++p)
                        if (p < np && s_penidx[p] == idx) dv += s_pen[p];
                    t2_push(t, v - 0.5f * dv + s_sc[beam], m * VOCAB + idx);
                }
            } else if (tid < KC) {
                // invalid row: constant sc -> best two flat idx m*V, m*V+1
                t2_push(t, s_sc[beam], m * VOCAB + tid);
            }
        }

        #pragma unroll
        for (int off = 32; off > 0; off >>= 1) {
            Top2 o;
            o.v1 = __shfl_down(t.v1, off); o.i1 = __shfl_down(t.i1, off);
            o.v2 = __shfl_down(t.v2, off); o.i2 = __shfl_down(t.i2, off);
            t2_merge(t, o);
        }
        if (tid == 0) {
            s_selv[g][0] = t.v1; s_seli[g][0] = t.i1 % VOCAB; s_selm[g][0] = t.i1 / VOCAB;
            s_selv[g][1] = t.v2; s_seli[g][1] = t.i2 % VOCAB; s_selm[g][1] = t.i2 / VOCAB;
        }
        __syncthreads();
    }

    // ---- outputs: scores[0,512) indices[512,1024) beams[1024,1536) overlap[1536,2560)
    if (tid < KC * NG) {                  // i = m*NG + g
        const int i = tid;
        const int m = i / NG, g = i % NG;
        out[(size_t)b * BEAM + i]        = s_selv[g][m];
        out[512 + (size_t)b * BEAM + i]  = (float)s_seli[g][m];
        out[1024 + (size_t)b * BEAM + i] = (float)(s_selm[g][m] * NG + g);
    }
    if (tid >= 16 && tid < 16 + NG * NG) {
        const int q  = tid - 16;
        const int g1 = q / NG, g2 = q % NG;
        int ov = 0;
        for (int m = 0; m < MB; ++m) {
            const int i1 = m * NG + g1, i2 = m * NG + g2;
            const int p1a = lastn[(size_t)b * BEAM + i1];
            const int p2a = lastn[(size_t)b * BEAM + i2];
            const int p1b = s_seli[g1][m];
            const int p2b = s_seli[g2][m];
            const int* mk1 = mask + ((size_t)b * BEAM + i1) * NGRAM;
            const int* mk2 = mask + ((size_t)b * BEAM + i2) * NGRAM;
            const bool e0 = (p1a == p2a) && (mk1[0] != 0) && (mk2[0] != 0);
            const bool e1 = (p1b == p2b) && (mk1[1] != 0) && (mk2[1] != 0);
            ov += (e0 && e1) ? 1 : 0;
        }
        out[1536 + (size_t)ob * (NG * NG) + q] =
            (overlap[(size_t)ob * (NG * NG) + q] + (float)ov) * 0.5f;
    }
}

extern "C" void kernel_launch(void* const* d_in, const int* in_sizes, int n_in,
                              void* d_out, int out_size, void* d_ws, size_t ws_size,
                              hipStream_t stream) {
    const float* lprobs  = (const float*)d_in[0];
    const float* scores  = (const float*)d_in[1];
    const float* overlap = (const float*)d_in[2];
    const int*   obi     = (const int*)d_in[3];
    const int*   lastn   = (const int*)d_in[4];
    const int*   mask    = (const int*)d_in[5];
    const int*   stepp   = (const int*)d_in[6];
    float*       out     = (float*)d_out;

    // ws layout: wscnt (512 i32) | wscv (512*CAP f32) | wsci (512*CAP i32)
    int*   wscnt = (int*)d_ws;
    float* wscv  = (float*)((char*)d_ws + ROWS * 4);
    int*   wsci  = (int*)((char*)d_ws + ROWS * 4 + (size_t)ROWS * CAP * 4);

    dbs_candidates<<<ROWS, 1024, 0, stream>>>(lprobs, mask, wscnt, wscv, wsci);
    dbs_final     <<<BSZ, 64, 0, stream>>>(scores, overlap, obi, lastn, mask, stepp,
                                           wscnt, wscv, wsci, out);
}